// Round 4
// baseline (2235.997 us; speedup 1.0000x reference)
//
#include <hip/hip_runtime.h>
#include <math.h>

#define NPTS 256
#define NB 8
#define CPL 4  // columns (and rows) per lane: 64 lanes * 4 = 256

#if __has_builtin(__builtin_amdgcn_sqrtf)
#define FSQRT __builtin_amdgcn_sqrtf
#else
#define FSQRT sqrtf
#endif

// Exact fp64 distance (contract off) for the final loss value.
__device__ __forceinline__ double dist3d(double ax, double ay, double az,
                                         double bx, double by, double bz) {
#pragma clang fp contract(off)
  double d0 = ax - bx;
  double d1 = ay - by;
  double d2 = az - bz;
  double s = d0 * d0;
  s = s + d1 * d1;
  s = s + d2 * d2;
  return sqrt(s);
}

__device__ __forceinline__ float distf(float ax, float ay, float az,
                                       float bx, float by, float bz) {
  float d0 = ax - bx, d1 = ay - by, d2 = az - bz;
  return FSQRT(d0 * d0 + d1 * d1 + d2 * d2);
}

// Wave64 min-reduce of a u32 via DPP (row_shr 1/2/4/8 + row_bcast 15/31),
// result broadcast via readlane(63). Pure VALU/SALU — no LDS traffic.
__device__ __forceinline__ unsigned wave_min_u32(unsigned x) {
  unsigned r = x;
  r = min(r, (unsigned)__builtin_amdgcn_update_dpp((int)r, (int)r, 0x111, 0xF, 0xF, false));
  r = min(r, (unsigned)__builtin_amdgcn_update_dpp((int)r, (int)r, 0x112, 0xF, 0xF, false));
  r = min(r, (unsigned)__builtin_amdgcn_update_dpp((int)r, (int)r, 0x114, 0xF, 0xF, false));
  r = min(r, (unsigned)__builtin_amdgcn_update_dpp((int)r, (int)r, 0x118, 0xF, 0xF, false));
  r = min(r, (unsigned)__builtin_amdgcn_update_dpp((int)r, (int)r, 0x142, 0xF, 0xF, false));
  r = min(r, (unsigned)__builtin_amdgcn_update_dpp((int)r, (int)r, 0x143, 0xF, 0xF, false));
  return (unsigned)__builtin_amdgcn_readlane((int)r, 63);
}

// Uniform (c, owner) gather via cndmask select + __shfl (round-2 proven).
__device__ __forceinline__ float sel4_shfl(const float a[CPL], int c, int owner) {
  float lo = (c & 1) ? a[1] : a[0];
  float hi = (c & 1) ? a[3] : a[2];
  float s = (c & 2) ? hi : lo;
  return __shfl(s, owner);
}
__device__ __forceinline__ int sel4i_shfl(const int a[CPL], int c, int owner) {
  int lo = (c & 1) ? a[1] : a[0];
  int hi = (c & 1) ? a[3] : a[2];
  int s = (c & 2) ? hi : lo;
  return __shfl(s, owner);
}

// One block = one 64-lane wave per batch sample. Full LAPJV:
// column reduction + greedy, augmenting row reduction (2 rounds),
// shortest augmenting path for the leftovers.
__global__ __launch_bounds__(64) void emd_lsa_kernel(
    const float* __restrict__ pred, const float* __restrict__ label,
    double* __restrict__ partial) {
  __shared__ float4 rowd[NPTS];     // {x0,x1,x2,u}
  __shared__ float ys0[NPTS], ys1[NPTS], ys2[NPTS];
  __shared__ float short_l[NPTS];   // shortest[] published for scanned cols
  __shared__ int path_l[NPTS];      // path[] published for scanned cols
  __shared__ int c4r_l[NPTS];       // col4row
  __shared__ int r4c_l[NPTS];       // row4col
  __shared__ int sr_l[NPTS];        // scanned-row flags
  __shared__ int bcfr[NPTS];        // greedy: best (lowest) col per row
  __shared__ int fq[NPTS];          // free-row queue

  const int lane = threadIdx.x;
  const int b = blockIdx.x;
  const float* xg = pred + (size_t)b * NPTS * 3;
  const float* yg = label + (size_t)b * NPTS * 3;

  float yc0[CPL], yc1[CPL], yc2[CPL];  // owned columns' coords
  float v_reg[CPL];                    // column duals
  int r4c_reg[CPL];                    // mirror of r4c_l for owned cols

#pragma unroll
  for (int c = 0; c < CPL; ++c) {
    int j = lane * CPL + c;
    rowd[j] = make_float4(xg[j * 3 + 0], xg[j * 3 + 1], xg[j * 3 + 2], 0.0f);
    float t0 = yg[j * 3 + 0], t1 = yg[j * 3 + 1], t2 = yg[j * 3 + 2];
    ys0[j] = t0; ys1[j] = t1; ys2[j] = t2;
    yc0[c] = t0; yc1[c] = t1; yc2[c] = t2;
    c4r_l[j] = -1;
    r4c_l[j] = -1;
    bcfr[j] = 0x7FFFFFFF;
  }
  __syncthreads();

  // ---- Column reduction: v[j] = min_i cost[i][j], argmin row. ----
  float cmin[CPL];
  int imin[CPL];
#pragma unroll
  for (int c = 0; c < CPL; ++c) { cmin[c] = 3.4e38f; imin[c] = -1; }
  for (int i = 0; i < NPTS; ++i) {
    float4 rd = rowd[i];  // broadcast read; independent iterations pipeline
#pragma unroll
    for (int c = 0; c < CPL; ++c) {
      float d = distf(rd.x, rd.y, rd.z, yc0[c], yc1[c], yc2[c]);
      bool upd = d < cmin[c];
      cmin[c] = upd ? d : cmin[c];
      imin[c] = upd ? i : imin[c];
    }
  }
#pragma unroll
  for (int c = 0; c < CPL; ++c) {
    v_reg[c] = cmin[c];
    atomicMin(&bcfr[imin[c]], lane * CPL + c);
  }
  __syncthreads();
#pragma unroll
  for (int c = 0; c < CPL; ++c) {
    int j = lane * CPL + c;
    if (bcfr[imin[c]] == j) {
      r4c_l[j] = imin[c];
      c4r_l[imin[c]] = j;
    }
  }
  __syncthreads();
#pragma unroll
  for (int c = 0; c < CPL; ++c) r4c_reg[c] = r4c_l[lane * CPL + c];
  __syncthreads();

  // ---- Build free-row queue via ballot compaction. ----
  int nf;
  {
    int4 cc = *(int4*)&c4r_l[lane * CPL];
    bool f0 = cc.x < 0, f1 = cc.y < 0, f2 = cc.z < 0, f3 = cc.w < 0;
    unsigned long long b0 = __ballot(f0), b1 = __ballot(f1);
    unsigned long long b2 = __ballot(f2), b3 = __ballot(f3);
    unsigned long long lt = (1ull << lane) - 1ull;
    int off = __popcll(b0 & lt) + __popcll(b1 & lt) + __popcll(b2 & lt) + __popcll(b3 & lt);
    if (f0) fq[off++] = lane * CPL + 0;
    if (f1) fq[off++] = lane * CPL + 1;
    if (f2) fq[off++] = lane * CPL + 2;
    if (f3) fq[off++] = lane * CPL + 3;
    nf = __popcll(b0) + __popcll(b1) + __popcll(b2) + __popcll(b3);
  }
  __syncthreads();

  // ---- Augmenting row reduction (LAPJV CARR), 2 rounds. ----
  for (int rnd = 0; rnd < 2; ++rnd) {
    int nf_new = 0, k = 0, guard = 0;
    while (k < nf && ++guard <= 1024) {
      int i = fq[k]; k++;          // uniform broadcast read
      float4 rd = rowd[i];
      float rr[CPL];
      unsigned kk[CPL];
      unsigned lk = 0xFFFFFFFFu;
#pragma unroll
      for (int c = 0; c < CPL; ++c) {
        float d = distf(rd.x, rd.y, rd.z, yc0[c], yc1[c], yc2[c]);
        rr[c] = d - v_reg[c];  // >= 0 by construction
        kk[c] = (__float_as_uint(fmaxf(rr[c], 0.0f)) & 0xFFFFFF00u) |
                (unsigned)(lane * CPL + c);
        lk = min(lk, kk[c]);
      }
      unsigned k1 = wave_min_u32(lk);
      int j1 = (int)(k1 & 0xFFu), c1 = j1 & (CPL - 1), o1 = j1 >> 2;
      float u1 = sel4_shfl(rr, c1, o1);          // exact value
      int i0 = sel4i_shfl(r4c_reg, c1, o1);      // current row of j1
      // mask j1, second min
      unsigned lk2 = 0xFFFFFFFFu;
#pragma unroll
      for (int c = 0; c < CPL; ++c) {
        unsigned kc = (lane * CPL + c == j1) ? 0xFFFFFFFFu : kk[c];
        lk2 = min(lk2, kc);
      }
      unsigned k2 = wave_min_u32(lk2);
      int j2 = (int)(k2 & 0xFFu);
      float u2 = sel4_shfl(rr, j2 & (CPL - 1), j2 >> 2);

      bool strict = u1 < u2;
      int jT = j1, iT = i0;
      if (strict) {
        if (lane == o1) v_reg[c1] -= (u2 - u1);
      } else if (i0 >= 0) {
        jT = j2;
        iT = sel4i_shfl(r4c_reg, j2 & (CPL - 1), j2 >> 2);
      }
      // assign i -> jT; dispossess iT if any
      if (lane == (jT >> 2)) { r4c_reg[jT & (CPL - 1)] = i; r4c_l[jT] = i; }
      if (lane == 0) {
        c4r_l[i] = jT;
        if (iT >= 0) c4r_l[iT] = -1;
        rowd[i].w = strict ? u2 : u1;  // row dual (keeps feasibility + CS)
      }
      if (iT >= 0) {
        if (strict) {
          k--;
          if (lane == 0) fq[k] = iT;   // reprocess immediately
        } else {
          if (lane == 0) fq[nf_new] = iT;  // defer to next round
          nf_new++;
        }
      }
    }
    nf = nf_new;
    __syncthreads();
  }

  // ---- Rebuild leftover free-row list (guard-proof). ----
  {
    int4 cc = *(int4*)&c4r_l[lane * CPL];
    bool f0 = cc.x < 0, f1 = cc.y < 0, f2 = cc.z < 0, f3 = cc.w < 0;
    unsigned long long b0 = __ballot(f0), b1 = __ballot(f1);
    unsigned long long b2 = __ballot(f2), b3 = __ballot(f3);
    unsigned long long lt = (1ull << lane) - 1ull;
    int off = __popcll(b0 & lt) + __popcll(b1 & lt) + __popcll(b2 & lt) + __popcll(b3 & lt);
    if (f0) fq[off++] = lane * CPL + 0;
    if (f1) fq[off++] = lane * CPL + 1;
    if (f2) fq[off++] = lane * CPL + 2;
    if (f3) fq[off++] = lane * CPL + 3;
    nf = __popcll(b0) + __popcll(b1) + __popcll(b2) + __popcll(b3);
  }
  __syncthreads();

  const float INF = 3.4e38f;

  // ---- Shortest augmenting path for each remaining free row (round-2). ----
  for (int t = 0; t < nf; ++t) {
    int cur_row = fq[t];  // uniform

    float shortest[CPL];
    int path_r[CPL];
    int scn[CPL];
#pragma unroll
    for (int c = 0; c < CPL; ++c) {
      shortest[c] = INF;
      path_r[c] = -1;
      scn[c] = 0;
      sr_l[lane * CPL + c] = 0;
    }
    __syncthreads();

    float min_val = 0.0f;
    int i = cur_row;
    int sink = -1;

    while (true) {
      sr_l[i] = 1;
      float4 rd = rowd[i];  // {x,y,z,u[i]} broadcast ds_read_b128
      float base = min_val - rd.w;
      unsigned lkey = 0xFFFFFFFFu;
#pragma unroll
      for (int c = 0; c < CPL; ++c) {
        float cst = distf(rd.x, rd.y, rd.z, yc0[c], yc1[c], yc2[c]);
        float r = (base + cst) - v_reg[c];
        bool upd = (r < shortest[c]) && !scn[c];
        shortest[c] = upd ? r : shortest[c];
        path_r[c] = upd ? i : path_r[c];
        float snn = fmaxf(shortest[c], 0.0f);
        unsigned k = (__float_as_uint(snn) & 0xFFFFFF00u) | (unsigned)(lane * CPL + c);
        k = scn[c] ? 0xFFFFFFFFu : k;
        lkey = min(lkey, k);
      }
      unsigned best = wave_min_u32(lkey);
      int jstar = (int)(best & 0xFFu);
      int csel = jstar & (CPL - 1);
      int owner = jstar >> 2;

      if (owner == lane) {
        scn[csel] = 1;
        short_l[jstar] = shortest[csel];
        path_l[jstar] = path_r[csel];
      }
      min_val = sel4_shfl(shortest, csel, owner);
      int nr = sel4i_shfl(r4c_reg, csel, owner);
      if (nr < 0) { sink = jstar; break; }
      i = nr;
    }
    __syncthreads();  // publish short_l / path_l / sr_l

    // Dual update (rows via LDS flags, cols via register state).
#pragma unroll
    for (int c = 0; c < CPL; ++c) {
      int row = lane * CPL + c;
      if (sr_l[row]) {
        float du = (row == cur_row) ? min_val : (min_val - short_l[c4r_l[row]]);
        rowd[row].w += du;
      }
      if (scn[c]) v_reg[c] -= min_val - shortest[c];
    }
    __syncthreads();

    if (lane == 0) {  // augment along the alternating path
      int jj = sink;
      while (true) {
        int ii = path_l[jj];
        r4c_l[jj] = ii;
        int tmp = c4r_l[ii];
        c4r_l[ii] = jj;
        jj = tmp;
        if (ii == cur_row) break;
      }
    }
    __syncthreads();
#pragma unroll
    for (int c = 0; c < CPL; ++c) r4c_reg[c] = r4c_l[lane * CPL + c];
    __syncthreads();
  }

  // ---- Final loss: exact fp64 matched distances. ----
  double s = 0.0;
#pragma unroll
  for (int c = 0; c < CPL; ++c) {
    int row = lane * CPL + c;
    int j = c4r_l[row];
    float4 rd = rowd[row];
    s += dist3d((double)rd.x, (double)rd.y, (double)rd.z,
                (double)ys0[j], (double)ys1[j], (double)ys2[j]);
  }
  for (int m = 1; m < 64; m <<= 1) s += __shfl_xor(s, m);
  if (lane == 0) partial[b] = s;
}

__global__ void emd_finalize_kernel(const double* __restrict__ partial,
                                    float* __restrict__ out) {
  if (threadIdx.x == 0 && blockIdx.x == 0) {
    double s = 0.0;
    for (int b = 0; b < NB; ++b) s += partial[b];
    out[0] = (float)(s / (double)(NB * NPTS));
  }
}

extern "C" void kernel_launch(void* const* d_in, const int* in_sizes, int n_in,
                              void* d_out, int out_size, void* d_ws, size_t ws_size,
                              hipStream_t stream) {
  const float* pred = (const float*)d_in[0];
  const float* label = (const float*)d_in[1];
  double* partial = (double*)d_ws;  // 8 doubles
  emd_lsa_kernel<<<NB, 64, 0, stream>>>(pred, label, partial);
  emd_finalize_kernel<<<1, 64, 0, stream>>>(partial, (float*)d_out);
}

// Round 5
// 1881.710 us; speedup vs baseline: 1.1883x; 1.1883x over previous
//
#include <hip/hip_runtime.h>
#include <math.h>

#define NPTS 256
#define NB 8
#define CPL 4      // columns (and rows) per lane: 64 lanes * 4 = 256
#define JROUNDS 8  // max parallel Jacobi auction rounds
#define JSTOP 6    // stop auction when free rows <= this

#if __has_builtin(__builtin_amdgcn_sqrtf)
#define FSQRT __builtin_amdgcn_sqrtf
#else
#define FSQRT sqrtf
#endif

// Exact fp64 distance (contract off) for the final loss value.
__device__ __forceinline__ double dist3d(double ax, double ay, double az,
                                         double bx, double by, double bz) {
#pragma clang fp contract(off)
  double d0 = ax - bx;
  double d1 = ay - by;
  double d2 = az - bz;
  double s = d0 * d0;
  s = s + d1 * d1;
  s = s + d2 * d2;
  return sqrt(s);
}

__device__ __forceinline__ float distf(float ax, float ay, float az,
                                       float bx, float by, float bz) {
  float d0 = ax - bx, d1 = ay - by, d2 = az - bz;
  return FSQRT(d0 * d0 + d1 * d1 + d2 * d2);
}

// Wave64 min-reduce of a u32 via DPP (row_shr 1/2/4/8 + row_bcast 15/31),
// result broadcast via readlane(63). Pure VALU/SALU — no LDS traffic.
__device__ __forceinline__ unsigned wave_min_u32(unsigned x) {
  unsigned r = x;
  r = min(r, (unsigned)__builtin_amdgcn_update_dpp((int)r, (int)r, 0x111, 0xF, 0xF, false));
  r = min(r, (unsigned)__builtin_amdgcn_update_dpp((int)r, (int)r, 0x112, 0xF, 0xF, false));
  r = min(r, (unsigned)__builtin_amdgcn_update_dpp((int)r, (int)r, 0x114, 0xF, 0xF, false));
  r = min(r, (unsigned)__builtin_amdgcn_update_dpp((int)r, (int)r, 0x118, 0xF, 0xF, false));
  r = min(r, (unsigned)__builtin_amdgcn_update_dpp((int)r, (int)r, 0x142, 0xF, 0xF, false));
  r = min(r, (unsigned)__builtin_amdgcn_update_dpp((int)r, (int)r, 0x143, 0xF, 0xF, false));
  return (unsigned)__builtin_amdgcn_readlane((int)r, 63);
}

// Uniform (c, owner) gather via cndmask select + __shfl (round-2 proven).
__device__ __forceinline__ float sel4_shfl(const float a[CPL], int c, int owner) {
  float lo = (c & 1) ? a[1] : a[0];
  float hi = (c & 1) ? a[3] : a[2];
  float s = (c & 2) ? hi : lo;
  return __shfl(s, owner);
}
__device__ __forceinline__ int sel4i_shfl(const int a[CPL], int c, int owner) {
  int lo = (c & 1) ? a[1] : a[0];
  int hi = (c & 1) ? a[3] : a[2];
  int s = (c & 2) ? hi : lo;
  return __shfl(s, owner);
}

// One block = one 64-lane wave per batch sample.
// Column reduction + greedy, parallel Jacobi auction rounds, then exact
// shortest-augmenting-path (round-2 proven) for the leftovers.
__global__ __launch_bounds__(64) void emd_lsa_kernel(
    const float* __restrict__ pred, const float* __restrict__ label,
    double* __restrict__ partial) {
  __shared__ float4 rowd[NPTS];   // {x0,x1,x2,u}
  __shared__ float4 colj[NPTS];   // {y0,y1,y2,v}
  __shared__ float short_l[NPTS]; // shortest[] published for scanned cols
  __shared__ int path_l[NPTS];    // path[] published for scanned cols
  __shared__ int c4r_l[NPTS];     // col4row
  __shared__ int r4c_l[NPTS];     // row4col
  __shared__ int sr_l[NPTS];      // scanned-row flags
  __shared__ int bidk[NPTS];      // greedy claims / auction bids
  __shared__ int fq[NPTS];        // free-row queue

  const int lane = threadIdx.x;
  const int b = blockIdx.x;
  const float* xg = pred + (size_t)b * NPTS * 3;
  const float* yg = label + (size_t)b * NPTS * 3;

  float rx[CPL], ry[CPL], rz[CPL];     // owned rows' coords
  float yc0[CPL], yc1[CPL], yc2[CPL];  // owned columns' coords
  float v_reg[CPL];                    // column duals (Dijkstra phase)
  int r4c_reg[CPL];                    // mirror of r4c_l for owned cols

#pragma unroll
  for (int c = 0; c < CPL; ++c) {
    int j = lane * CPL + c;
    float x0 = xg[j * 3 + 0], x1 = xg[j * 3 + 1], x2 = xg[j * 3 + 2];
    rx[c] = x0; ry[c] = x1; rz[c] = x2;
    rowd[j] = make_float4(x0, x1, x2, 0.0f);
    float t0 = yg[j * 3 + 0], t1 = yg[j * 3 + 1], t2 = yg[j * 3 + 2];
    yc0[c] = t0; yc1[c] = t1; yc2[c] = t2;
    c4r_l[j] = -1;
    r4c_l[j] = -1;
    bidk[j] = 0x7FFFFFFF;
  }
  __syncthreads();

  // ---- Column reduction: v[j] = min_i cost[i][j], argmin row. ----
  float cmin[CPL];
  int imin[CPL];
#pragma unroll
  for (int c = 0; c < CPL; ++c) { cmin[c] = 3.4e38f; imin[c] = -1; }
  for (int i = 0; i < NPTS; ++i) {
    float4 rd = rowd[i];  // broadcast read; independent iterations pipeline
#pragma unroll
    for (int c = 0; c < CPL; ++c) {
      float d = distf(rd.x, rd.y, rd.z, yc0[c], yc1[c], yc2[c]);
      bool upd = d < cmin[c];
      cmin[c] = upd ? d : cmin[c];
      imin[c] = upd ? i : imin[c];
    }
  }
#pragma unroll
  for (int c = 0; c < CPL; ++c) {
    int j = lane * CPL + c;
    v_reg[c] = cmin[c];
    colj[j] = make_float4(yc0[c], yc1[c], yc2[c], cmin[c]);
    atomicMin(&bidk[imin[c]], j);  // greedy claim (bidk indexed by ROW here)
  }
  __syncthreads();
#pragma unroll
  for (int c = 0; c < CPL; ++c) {
    int j = lane * CPL + c;
    if (bidk[imin[c]] == j) {
      r4c_l[j] = imin[c];
      c4r_l[imin[c]] = j;
    }
  }
  __syncthreads();

  // Free-row count.
  int nf;
  {
    int4 cc = *(int4*)&c4r_l[lane * CPL];
    nf = __popcll(__ballot(cc.x < 0)) + __popcll(__ballot(cc.y < 0)) +
         __popcll(__ballot(cc.z < 0)) + __popcll(__ballot(cc.w < 0));
  }

  // ---- Parallel Jacobi auction rounds. ----
  for (int rnd = 0; rnd < JROUNDS && nf > JSTOP; ++rnd) {
    *(int4*)&bidk[lane * CPL] = make_int4(0x7FFFFFFF, 0x7FFFFFFF, 0x7FFFFFFF, 0x7FFFFFFF);
    bool fr[CPL];
#pragma unroll
    for (int c = 0; c < CPL; ++c) fr[c] = (c4r_l[lane * CPL + c] < 0);
    __syncthreads();

    // Bidding: each lane scans its 4 rows against all 256 cols (broadcast).
    float m1[CPL], m2[CPL];
    int j1[CPL];
#pragma unroll
    for (int c = 0; c < CPL; ++c) { m1[c] = 3.4e38f; m2[c] = 3.4e38f; j1[c] = -1; }
    for (int j = 0; j < NPTS; ++j) {
      float4 cj = colj[j];
#pragma unroll
      for (int c = 0; c < CPL; ++c) {
        float d = distf(rx[c], ry[c], rz[c], cj.x, cj.y, cj.z) - cj.w;
        bool b1 = d < m1[c];
        float nm2 = b1 ? m1[c] : fminf(m2[c], d);
        m1[c] = b1 ? d : m1[c];
        j1[c] = b1 ? j : j1[c];
        m2[c] = nm2;
      }
    }
#pragma unroll
    for (int c = 0; c < CPL; ++c) {
      if (fr[c]) {
        unsigned key = (__float_as_uint(fmaxf(m1[c], 0.0f)) & 0xFFFFFF00u) |
                       (unsigned)(lane * CPL + c);
        atomicMin(&bidk[j1[c]], (int)key);
      }
    }
    __syncthreads();

    // Resolution: winning row's lane commits (exclusive per column).
#pragma unroll
    for (int c = 0; c < CPL; ++c) {
      int row = lane * CPL + c;
      if (fr[c] && (bidk[j1[c]] & 0xFF) == row) {
        int j = j1[c];
        int old = r4c_l[j];
        r4c_l[j] = row;
        c4r_l[row] = j;
        if (old >= 0) c4r_l[old] = -1;
        rowd[row].w = m2[c];          // u[i] = second min (keeps rc >= 0)
        colj[j].w += m1[c] - m2[c];   // v[j] decreases; edge (row,j) tight
      }
    }
    __syncthreads();
    {
      int4 cc = *(int4*)&c4r_l[lane * CPL];
      nf = __popcll(__ballot(cc.x < 0)) + __popcll(__ballot(cc.y < 0)) +
           __popcll(__ballot(cc.z < 0)) + __popcll(__ballot(cc.w < 0));
    }
  }

  // Refresh register mirrors; build leftover free-row queue.
#pragma unroll
  for (int c = 0; c < CPL; ++c) {
    v_reg[c] = colj[lane * CPL + c].w;
    r4c_reg[c] = r4c_l[lane * CPL + c];
  }
  {
    int4 cc = *(int4*)&c4r_l[lane * CPL];
    bool f0 = cc.x < 0, f1 = cc.y < 0, f2 = cc.z < 0, f3 = cc.w < 0;
    unsigned long long b0 = __ballot(f0), b1 = __ballot(f1);
    unsigned long long b2 = __ballot(f2), b3 = __ballot(f3);
    unsigned long long lt = (1ull << lane) - 1ull;
    int off = __popcll(b0 & lt) + __popcll(b1 & lt) + __popcll(b2 & lt) + __popcll(b3 & lt);
    if (f0) fq[off++] = lane * CPL + 0;
    if (f1) fq[off++] = lane * CPL + 1;
    if (f2) fq[off++] = lane * CPL + 2;
    if (f3) fq[off++] = lane * CPL + 3;
    nf = __popcll(b0) + __popcll(b1) + __popcll(b2) + __popcll(b3);
  }
  __syncthreads();

  const float INF = 3.4e38f;

  // ---- Shortest augmenting path for each remaining free row (round-2). ----
  for (int t = 0; t < nf; ++t) {
    int cur_row = fq[t];  // uniform

    float shortest[CPL];
    int path_r[CPL];
    int scn[CPL];
#pragma unroll
    for (int c = 0; c < CPL; ++c) {
      shortest[c] = INF;
      path_r[c] = -1;
      scn[c] = 0;
      sr_l[lane * CPL + c] = 0;
    }
    __syncthreads();

    float min_val = 0.0f;
    int i = cur_row;
    int sink = -1;

    while (true) {
      sr_l[i] = 1;
      float4 rd = rowd[i];  // {x,y,z,u[i]} broadcast ds_read_b128
      float base = min_val - rd.w;
      unsigned lkey = 0xFFFFFFFFu;
#pragma unroll
      for (int c = 0; c < CPL; ++c) {
        float cst = distf(rd.x, rd.y, rd.z, yc0[c], yc1[c], yc2[c]);
        float r = (base + cst) - v_reg[c];
        bool upd = (r < shortest[c]) && !scn[c];
        shortest[c] = upd ? r : shortest[c];
        path_r[c] = upd ? i : path_r[c];
        float snn = fmaxf(shortest[c], 0.0f);
        unsigned k = (__float_as_uint(snn) & 0xFFFFFF00u) | (unsigned)(lane * CPL + c);
        k = scn[c] ? 0xFFFFFFFFu : k;
        lkey = min(lkey, k);
      }
      unsigned best = wave_min_u32(lkey);
      int jstar = (int)(best & 0xFFu);
      int csel = jstar & (CPL - 1);
      int owner = jstar >> 2;

      if (owner == lane) {
        scn[csel] = 1;
        short_l[jstar] = shortest[csel];
        path_l[jstar] = path_r[csel];
      }
      min_val = sel4_shfl(shortest, csel, owner);
      int nr = sel4i_shfl(r4c_reg, csel, owner);
      if (nr < 0) { sink = jstar; break; }
      i = nr;
    }
    __syncthreads();  // publish short_l / path_l / sr_l

    // Dual update (rows via LDS flags, cols via register state).
#pragma unroll
    for (int c = 0; c < CPL; ++c) {
      int row = lane * CPL + c;
      if (sr_l[row]) {
        float du = (row == cur_row) ? min_val : (min_val - short_l[c4r_l[row]]);
        rowd[row].w += du;
      }
      if (scn[c]) v_reg[c] -= min_val - shortest[c];
    }
    __syncthreads();

    if (lane == 0) {  // augment along the alternating path
      int jj = sink;
      while (true) {
        int ii = path_l[jj];
        r4c_l[jj] = ii;
        int tmp = c4r_l[ii];
        c4r_l[ii] = jj;
        jj = tmp;
        if (ii == cur_row) break;
      }
    }
    __syncthreads();
#pragma unroll
    for (int c = 0; c < CPL; ++c) r4c_reg[c] = r4c_l[lane * CPL + c];
    __syncthreads();
  }

  // ---- Final loss: exact fp64 matched distances. ----
  double s = 0.0;
#pragma unroll
  for (int c = 0; c < CPL; ++c) {
    int row = lane * CPL + c;
    int j = c4r_l[row];
    float4 cj = colj[j];
    s += dist3d((double)rx[c], (double)ry[c], (double)rz[c],
                (double)cj.x, (double)cj.y, (double)cj.z);
  }
  for (int m = 1; m < 64; m <<= 1) s += __shfl_xor(s, m);
  if (lane == 0) partial[b] = s;
}

__global__ void emd_finalize_kernel(const double* __restrict__ partial,
                                    float* __restrict__ out) {
  if (threadIdx.x == 0 && blockIdx.x == 0) {
    double s = 0.0;
    for (int b = 0; b < NB; ++b) s += partial[b];
    out[0] = (float)(s / (double)(NB * NPTS));
  }
}

extern "C" void kernel_launch(void* const* d_in, const int* in_sizes, int n_in,
                              void* d_out, int out_size, void* d_ws, size_t ws_size,
                              hipStream_t stream) {
  const float* pred = (const float*)d_in[0];
  const float* label = (const float*)d_in[1];
  double* partial = (double*)d_ws;  // 8 doubles
  emd_lsa_kernel<<<NB, 64, 0, stream>>>(pred, label, partial);
  emd_finalize_kernel<<<1, 64, 0, stream>>>(partial, (float*)d_out);
}

// Round 6
// 1419.633 us; speedup vs baseline: 1.5751x; 1.3255x over previous
//
#include <hip/hip_runtime.h>
#include <math.h>

#define NPTS 256
#define NB 8

#if __has_builtin(__builtin_amdgcn_sqrtf)
#define FSQRT __builtin_amdgcn_sqrtf
#else
#define FSQRT sqrtf
#endif

// Exact fp64 distance (contract off) for the final loss value.
__device__ __forceinline__ double dist3d(double ax, double ay, double az,
                                         double bx, double by, double bz) {
#pragma clang fp contract(off)
  double d0 = ax - bx;
  double d1 = ay - by;
  double d2 = az - bz;
  double s = d0 * d0;
  s = s + d1 * d1;
  s = s + d2 * d2;
  return sqrt(s);
}

__device__ __forceinline__ float distf(float ax, float ay, float az,
                                       float bx, float by, float bz) {
  float d0 = ax - bx, d1 = ay - by, d2 = az - bz;
  return FSQRT(d0 * d0 + d1 * d1 + d2 * d2);
}

// Wave64 min-reduce of a u32 via DPP (row_shr 1/2/4/8 + row_bcast 15/31),
// broadcast via readlane(63). Pure VALU/SALU — no LDS traffic.
__device__ __forceinline__ unsigned wave_min_u32(unsigned x) {
  unsigned r = x;
  r = min(r, (unsigned)__builtin_amdgcn_update_dpp((int)r, (int)r, 0x111, 0xF, 0xF, false));
  r = min(r, (unsigned)__builtin_amdgcn_update_dpp((int)r, (int)r, 0x112, 0xF, 0xF, false));
  r = min(r, (unsigned)__builtin_amdgcn_update_dpp((int)r, (int)r, 0x114, 0xF, 0xF, false));
  r = min(r, (unsigned)__builtin_amdgcn_update_dpp((int)r, (int)r, 0x118, 0xF, 0xF, false));
  r = min(r, (unsigned)__builtin_amdgcn_update_dpp((int)r, (int)r, 0x142, 0xF, 0xF, false));
  r = min(r, (unsigned)__builtin_amdgcn_update_dpp((int)r, (int)r, 0x143, 0xF, 0xF, false));
  return (unsigned)__builtin_amdgcn_readlane((int)r, 63);
}

// One block = one 64-lane wave per batch sample. Round-2 algorithm (column
// reduction + greedy + shortest augmenting path), with the inner Dijkstra
// restructured: speculative per-lane candidate-row prefetch overlapped with
// the key butterfly, winner state broadcast via v_readlane (no bpermute,
// no serial ds_read on the critical path).
__global__ __launch_bounds__(64) void emd_lsa_kernel(
    const float* __restrict__ pred, const float* __restrict__ label,
    double* __restrict__ partial) {
  __shared__ float4 rowd[NPTS];   // {x0,x1,x2,u}
  __shared__ float ys0[NPTS], ys1[NPTS], ys2[NPTS];
  __shared__ float short_l[NPTS]; // shortest[] for scanned cols
  __shared__ int path_l[NPTS];    // path[] for scanned cols
  __shared__ int c4r_l[NPTS];     // col4row
  __shared__ int r4c_l[NPTS];     // row4col
  __shared__ int sr_l[NPTS];      // scanned-row flags
  __shared__ int bcfr[NPTS];      // greedy claims
  __shared__ int fq[NPTS];        // free-row queue

  const int lane = threadIdx.x;
  const int b = blockIdx.x;
  const float* xg = pred + (size_t)b * NPTS * 3;
  const float* yg = label + (size_t)b * NPTS * 3;

  const int cid0 = lane * 4, cid1 = cid0 + 1, cid2 = cid0 + 2, cid3 = cid0 + 3;

  // Owned columns' coords / duals / row4col mirrors — explicit scalars only.
  float q0x, q0y, q0z, q1x, q1y, q1z, q2x, q2y, q2z, q3x, q3y, q3z;
  float vv0, vv1, vv2, vv3;
  int rc0, rc1, rc2, rc3;

#define INITC(c) { int j = cid##c; \
    rowd[j] = make_float4(xg[j*3+0], xg[j*3+1], xg[j*3+2], 0.0f); \
    float t0 = yg[j*3+0], t1 = yg[j*3+1], t2 = yg[j*3+2]; \
    ys0[j] = t0; ys1[j] = t1; ys2[j] = t2; \
    q##c##x = t0; q##c##y = t1; q##c##z = t2; \
    c4r_l[j] = -1; r4c_l[j] = -1; bcfr[j] = 0x7FFFFFFF; }
  INITC(0) INITC(1) INITC(2) INITC(3)
#undef INITC
  __syncthreads();

  // ---- Column reduction: v[j] = min_i cost[i][j], argmin row. ----
  float mm0 = 3.4e38f, mm1 = 3.4e38f, mm2 = 3.4e38f, mm3 = 3.4e38f;
  int im0 = -1, im1 = -1, im2 = -1, im3 = -1;
  for (int i = 0; i < NPTS; ++i) {
    float4 rd = rowd[i];  // broadcast read; independent iterations pipeline
#define CRED(c) { float d = distf(rd.x, rd.y, rd.z, q##c##x, q##c##y, q##c##z); \
    bool u_ = d < mm##c; mm##c = u_ ? d : mm##c; im##c = u_ ? i : im##c; }
    CRED(0) CRED(1) CRED(2) CRED(3)
#undef CRED
  }
  vv0 = mm0; vv1 = mm1; vv2 = mm2; vv3 = mm3;
  atomicMin(&bcfr[im0], cid0);
  atomicMin(&bcfr[im1], cid1);
  atomicMin(&bcfr[im2], cid2);
  atomicMin(&bcfr[im3], cid3);
  __syncthreads();
  // Greedy: col j gets its argmin row iff j is the lowest col claiming it.
  if (bcfr[im0] == cid0) { r4c_l[cid0] = im0; c4r_l[im0] = cid0; }
  if (bcfr[im1] == cid1) { r4c_l[cid1] = im1; c4r_l[im1] = cid1; }
  if (bcfr[im2] == cid2) { r4c_l[cid2] = im2; c4r_l[im2] = cid2; }
  if (bcfr[im3] == cid3) { r4c_l[cid3] = im3; c4r_l[im3] = cid3; }
  __syncthreads();
  rc0 = r4c_l[cid0]; rc1 = r4c_l[cid1]; rc2 = r4c_l[cid2]; rc3 = r4c_l[cid3];

  // ---- Build free-row queue via ballot compaction. ----
  int nf;
  {
    int4 cc = *(int4*)&c4r_l[cid0];
    bool f0 = cc.x < 0, f1 = cc.y < 0, f2 = cc.z < 0, f3 = cc.w < 0;
    unsigned long long b0 = __ballot(f0), b1 = __ballot(f1);
    unsigned long long b2 = __ballot(f2), b3 = __ballot(f3);
    unsigned long long lt = (1ull << lane) - 1ull;
    int off = __popcll(b0 & lt) + __popcll(b1 & lt) + __popcll(b2 & lt) + __popcll(b3 & lt);
    if (f0) fq[off++] = cid0;
    if (f1) fq[off++] = cid1;
    if (f2) fq[off++] = cid2;
    if (f3) fq[off++] = cid3;
    nf = __popcll(b0) + __popcll(b1) + __popcll(b2) + __popcll(b3);
  }
  __syncthreads();

  const float INF = 3.4e38f;

  // ---- Shortest augmenting path for each free row. ----
  for (int t = 0; t < nf; ++t) {
    int cur_row = fq[t];  // uniform broadcast

    float sh0 = INF, sh1 = INF, sh2 = INF, sh3 = INF;
    int pp0 = -1, pp1 = -1, pp2 = -1, pp3 = -1;
    int sc0 = 0, sc1 = 0, sc2 = 0, sc3 = 0;
    *(int4*)&sr_l[cid0] = make_int4(0, 0, 0, 0);
    __syncthreads();

    float min_val = 0.0f;
    int i = cur_row;
    int sink = -1;
    float xi, yi, zi, ui;
    { float4 r0 = rowd[cur_row]; xi = r0.x; yi = r0.y; zi = r0.z; ui = r0.w; }

    while (true) {
      sr_l[i] = 1;  // same addr+value from all lanes
      float base = min_val - ui;
      unsigned k0, k1, k2, k3;
#define SSTEP(c) { float d = distf(xi, yi, zi, q##c##x, q##c##y, q##c##z); \
      float r = (base + d) - vv##c; \
      bool u_ = (r < sh##c) && (sc##c == 0); \
      sh##c = u_ ? r : sh##c; \
      pp##c = u_ ? i : pp##c; \
      unsigned kk = (__float_as_uint(fmaxf(sh##c, 0.0f)) & 0xFFFFFF00u) | (unsigned)cid##c; \
      k##c = sc##c ? 0xFFFFFFFFu : kk; }
      SSTEP(0) SSTEP(1) SSTEP(2) SSTEP(3)
#undef SSTEP
      // Local 4-way tournament (keys carry colid; ties impossible).
      bool t01 = k1 < k0;
      unsigned ka = t01 ? k1 : k0; int na = t01 ? rc1 : rc0;
      float ea = t01 ? sh1 : sh0;  int pa = t01 ? pp1 : pp0;
      bool t23 = k3 < k2;
      unsigned kb = t23 ? k3 : k2; int nb2 = t23 ? rc3 : rc2;
      float eb = t23 ? sh3 : sh2;  int pb = t23 ? pp3 : pp2;
      bool tf = kb < ka;
      unsigned lkey = tf ? kb : ka; int nl = tf ? nb2 : na;
      float el = tf ? eb : ea;     int pl = tf ? pb : pa;

      // Speculative prefetch of this lane's candidate next-row (overlaps
      // the butterfly; the winner's data lands in the winner's registers).
      float4 pre = rowd[nl < 0 ? 0 : nl];

      unsigned best = wave_min_u32(lkey);  // uniform after readlane(63)
      int jstar = (int)(best & 0xFFu);
      int w = jstar >> 2;  // winner lane; its tournament pick == jstar&3

      int nr = __builtin_amdgcn_readlane(nl, w);
      min_val = __int_as_float(__builtin_amdgcn_readlane(__float_as_int(el), w));
      int pj = __builtin_amdgcn_readlane(pl, w);

      short_l[jstar] = min_val;  // same addr+value from all lanes
      path_l[jstar] = pj;
      sc0 |= (cid0 == jstar); sc1 |= (cid1 == jstar);
      sc2 |= (cid2 == jstar); sc3 |= (cid3 == jstar);

      if (nr < 0) { sink = jstar; break; }
      i = nr;
      xi = __int_as_float(__builtin_amdgcn_readlane(__float_as_int(pre.x), w));
      yi = __int_as_float(__builtin_amdgcn_readlane(__float_as_int(pre.y), w));
      zi = __int_as_float(__builtin_amdgcn_readlane(__float_as_int(pre.z), w));
      ui = __int_as_float(__builtin_amdgcn_readlane(__float_as_int(pre.w), w));
    }
    __syncthreads();  // publish short_l / path_l / sr_l

    // Dual update (rows via LDS flags, cols via register state).
#define DUALU(c) { int row = cid##c; \
      if (sr_l[row]) { \
        float du = (row == cur_row) ? min_val : (min_val - short_l[c4r_l[row]]); \
        rowd[row].w += du; } \
      if (sc##c) vv##c -= min_val - sh##c; }
    DUALU(0) DUALU(1) DUALU(2) DUALU(3)
#undef DUALU
    __syncthreads();

    if (lane == 0) {  // augment along the alternating path
      int jj = sink;
      while (true) {
        int ii = path_l[jj];
        r4c_l[jj] = ii;
        int tmp = c4r_l[ii];
        c4r_l[ii] = jj;
        jj = tmp;
        if (ii == cur_row) break;
      }
    }
    __syncthreads();
    rc0 = r4c_l[cid0]; rc1 = r4c_l[cid1]; rc2 = r4c_l[cid2]; rc3 = r4c_l[cid3];
    __syncthreads();
  }

  // ---- Final loss: exact fp64 matched distances. ----
  double s = 0.0;
#define FIN(c) { int row = cid##c; int j = c4r_l[row]; float4 rd = rowd[row]; \
    s += dist3d((double)rd.x, (double)rd.y, (double)rd.z, \
                (double)ys0[j], (double)ys1[j], (double)ys2[j]); }
  FIN(0) FIN(1) FIN(2) FIN(3)
#undef FIN
  for (int m = 1; m < 64; m <<= 1) s += __shfl_xor(s, m);
  if (lane == 0) partial[b] = s;
}

__global__ void emd_finalize_kernel(const double* __restrict__ partial,
                                    float* __restrict__ out) {
  if (threadIdx.x == 0 && blockIdx.x == 0) {
    double s = 0.0;
    for (int b = 0; b < NB; ++b) s += partial[b];
    out[0] = (float)(s / (double)(NB * NPTS));
  }
}

extern "C" void kernel_launch(void* const* d_in, const int* in_sizes, int n_in,
                              void* d_out, int out_size, void* d_ws, size_t ws_size,
                              hipStream_t stream) {
  const float* pred = (const float*)d_in[0];
  const float* label = (const float*)d_in[1];
  double* partial = (double*)d_ws;  // 8 doubles
  emd_lsa_kernel<<<NB, 64, 0, stream>>>(pred, label, partial);
  emd_finalize_kernel<<<1, 64, 0, stream>>>(partial, (float*)d_out);
}

// Round 7
// 1352.630 us; speedup vs baseline: 1.6531x; 1.0495x over previous
//
#include <hip/hip_runtime.h>
#include <math.h>

#define NPTS 256
#define NB 8

#if __has_builtin(__builtin_amdgcn_sqrtf)
#define FSQRT __builtin_amdgcn_sqrtf
#else
#define FSQRT sqrtf
#endif

// Exact fp64 distance (contract off) for the final loss value.
__device__ __forceinline__ double dist3d(double ax, double ay, double az,
                                         double bx, double by, double bz) {
#pragma clang fp contract(off)
  double d0 = ax - bx;
  double d1 = ay - by;
  double d2 = az - bz;
  double s = d0 * d0;
  s = s + d1 * d1;
  s = s + d2 * d2;
  return sqrt(s);
}

__device__ __forceinline__ float distf(float ax, float ay, float az,
                                       float bx, float by, float bz) {
  float d0 = ax - bx, d1 = ay - by, d2 = az - bz;
  return FSQRT(d0 * d0 + d1 * d1 + d2 * d2);
}

// Wave64 min-reduce of a u32 via DPP (row_shr 1/2/4/8 + row_bcast 15/31),
// broadcast via readlane(63). Pure VALU/SALU — no LDS traffic.
__device__ __forceinline__ unsigned wave_min_u32(unsigned x) {
  unsigned r = x;
  r = min(r, (unsigned)__builtin_amdgcn_update_dpp((int)r, (int)r, 0x111, 0xF, 0xF, false));
  r = min(r, (unsigned)__builtin_amdgcn_update_dpp((int)r, (int)r, 0x112, 0xF, 0xF, false));
  r = min(r, (unsigned)__builtin_amdgcn_update_dpp((int)r, (int)r, 0x114, 0xF, 0xF, false));
  r = min(r, (unsigned)__builtin_amdgcn_update_dpp((int)r, (int)r, 0x118, 0xF, 0xF, false));
  r = min(r, (unsigned)__builtin_amdgcn_update_dpp((int)r, (int)r, 0x142, 0xF, 0xF, false));
  r = min(r, (unsigned)__builtin_amdgcn_update_dpp((int)r, (int)r, 0x143, 0xF, 0xF, false));
  return (unsigned)__builtin_amdgcn_readlane((int)r, 63);
}

// One block = one 64-lane wave per batch sample. Round-2 algorithm (column
// reduction + greedy + shortest augmenting path). Inner Dijkstra has ZERO
// LDS reads: assigned-row records are cached in registers once per search
// (constant during a search); winner state broadcasts via v_readlane.
__global__ __launch_bounds__(64) void emd_lsa_kernel(
    const float* __restrict__ pred, const float* __restrict__ label,
    double* __restrict__ partial) {
  __shared__ float4 rowd[NPTS];   // {x0,x1,x2,u}
  __shared__ float ys0[NPTS], ys1[NPTS], ys2[NPTS];
  __shared__ float short_l[NPTS]; // shortest[] for scanned cols
  __shared__ int path_l[NPTS];    // path[] for scanned cols
  __shared__ int c4r_l[NPTS];     // col4row
  __shared__ int r4c_l[NPTS];     // row4col
  __shared__ int sr_l[NPTS];      // scanned-row flags
  __shared__ int bcfr[NPTS];      // greedy claims
  __shared__ int fq[NPTS];        // free-row queue

  const int lane = threadIdx.x;
  const int b = blockIdx.x;
  const float* xg = pred + (size_t)b * NPTS * 3;
  const float* yg = label + (size_t)b * NPTS * 3;

  const int cid0 = lane * 4, cid1 = cid0 + 1, cid2 = cid0 + 2, cid3 = cid0 + 3;

  float q0x, q0y, q0z, q1x, q1y, q1z, q2x, q2y, q2z, q3x, q3y, q3z;
  float vv0, vv1, vv2, vv3;
  int rc0, rc1, rc2, rc3;

#define INITC(c) { int j = cid##c; \
    rowd[j] = make_float4(xg[j*3+0], xg[j*3+1], xg[j*3+2], 0.0f); \
    float t0 = yg[j*3+0], t1 = yg[j*3+1], t2 = yg[j*3+2]; \
    ys0[j] = t0; ys1[j] = t1; ys2[j] = t2; \
    q##c##x = t0; q##c##y = t1; q##c##z = t2; \
    c4r_l[j] = -1; r4c_l[j] = -1; bcfr[j] = 0x7FFFFFFF; }
  INITC(0) INITC(1) INITC(2) INITC(3)
#undef INITC
  __syncthreads();

  // ---- Column reduction: v[j] = min_i cost[i][j], argmin row. ----
  float mm0 = 3.4e38f, mm1 = 3.4e38f, mm2 = 3.4e38f, mm3 = 3.4e38f;
  int im0 = -1, im1 = -1, im2 = -1, im3 = -1;
  for (int i = 0; i < NPTS; ++i) {
    float4 rd = rowd[i];  // broadcast read; independent iterations pipeline
#define CRED(c) { float d = distf(rd.x, rd.y, rd.z, q##c##x, q##c##y, q##c##z); \
    bool u_ = d < mm##c; mm##c = u_ ? d : mm##c; im##c = u_ ? i : im##c; }
    CRED(0) CRED(1) CRED(2) CRED(3)
#undef CRED
  }
  vv0 = mm0; vv1 = mm1; vv2 = mm2; vv3 = mm3;
  atomicMin(&bcfr[im0], cid0);
  atomicMin(&bcfr[im1], cid1);
  atomicMin(&bcfr[im2], cid2);
  atomicMin(&bcfr[im3], cid3);
  __syncthreads();
  if (bcfr[im0] == cid0) { r4c_l[cid0] = im0; c4r_l[im0] = cid0; }
  if (bcfr[im1] == cid1) { r4c_l[cid1] = im1; c4r_l[im1] = cid1; }
  if (bcfr[im2] == cid2) { r4c_l[cid2] = im2; c4r_l[im2] = cid2; }
  if (bcfr[im3] == cid3) { r4c_l[cid3] = im3; c4r_l[im3] = cid3; }
  __syncthreads();
  rc0 = r4c_l[cid0]; rc1 = r4c_l[cid1]; rc2 = r4c_l[cid2]; rc3 = r4c_l[cid3];

  // ---- Build free-row queue via ballot compaction. ----
  int nf;
  {
    int4 cc = *(int4*)&c4r_l[cid0];
    bool f0 = cc.x < 0, f1 = cc.y < 0, f2 = cc.z < 0, f3 = cc.w < 0;
    unsigned long long b0 = __ballot(f0), b1 = __ballot(f1);
    unsigned long long b2 = __ballot(f2), b3 = __ballot(f3);
    unsigned long long lt = (1ull << lane) - 1ull;
    int off = __popcll(b0 & lt) + __popcll(b1 & lt) + __popcll(b2 & lt) + __popcll(b3 & lt);
    if (f0) fq[off++] = cid0;
    if (f1) fq[off++] = cid1;
    if (f2) fq[off++] = cid2;
    if (f3) fq[off++] = cid3;
    nf = __popcll(b0) + __popcll(b1) + __popcll(b2) + __popcll(b3);
  }
  __syncthreads();

  const float INF = 3.4e38f;

  // ---- Shortest augmenting path for each free row. ----
  for (int t = 0; t < nf; ++t) {
    int cur_row = fq[t];  // uniform broadcast

    float sh0 = INF, sh1 = INF, sh2 = INF, sh3 = INF;
    int pp0 = -1, pp1 = -1, pp2 = -1, pp3 = -1;
    int sc0 = 0, sc1 = 0, sc2 = 0, sc3 = 0;
    *(int4*)&sr_l[cid0] = make_int4(0, 0, 0, 0);

    // Cache assigned-row records for owned columns: constant during the
    // search (duals/assignment change only between searches). Once per
    // search, off the iteration critical path.
    float4 cr0 = rowd[rc0 < 0 ? 0 : rc0];
    float4 cr1 = rowd[rc1 < 0 ? 0 : rc1];
    float4 cr2 = rowd[rc2 < 0 ? 0 : rc2];
    float4 cr3 = rowd[rc3 < 0 ? 0 : rc3];

    float xi, yi, zi, ui;
    { float4 r0 = rowd[cur_row]; xi = r0.x; yi = r0.y; zi = r0.z; ui = r0.w; }
    __syncthreads();

    float min_val = 0.0f;
    int i = cur_row;
    int sink = -1;

    while (true) {
      sr_l[i] = 1;  // same addr+value from all lanes (write-collapse)
      float base = min_val - ui;
      unsigned k0, k1, k2, k3;
#define SSTEP(c) { float d = distf(xi, yi, zi, q##c##x, q##c##y, q##c##z); \
      float r = (base + d) - vv##c; \
      bool u_ = (r < sh##c) && (sc##c == 0); \
      sh##c = u_ ? r : sh##c; \
      pp##c = u_ ? i : pp##c; \
      unsigned kk = (__float_as_uint(fmaxf(sh##c, 0.0f)) & 0xFFFFFF00u) | (unsigned)cid##c; \
      k##c = sc##c ? 0xFFFFFFFFu : kk; }
      SSTEP(0) SSTEP(1) SSTEP(2) SSTEP(3)
#undef SSTEP
      // Local 4-way tournament; payload selects run parallel to the key ops.
      bool t01 = k1 < k0;
      unsigned ka = t01 ? k1 : k0;
      float ea = t01 ? sh1 : sh0; int pa = t01 ? pp1 : pp0; int na = t01 ? rc1 : rc0;
      float axa = t01 ? cr1.x : cr0.x, aya = t01 ? cr1.y : cr0.y;
      float aza = t01 ? cr1.z : cr0.z, aua = t01 ? cr1.w : cr0.w;
      bool t23 = k3 < k2;
      unsigned kb = t23 ? k3 : k2;
      float eb = t23 ? sh3 : sh2; int pb = t23 ? pp3 : pp2; int nb2 = t23 ? rc3 : rc2;
      float axb = t23 ? cr3.x : cr2.x, ayb = t23 ? cr3.y : cr2.y;
      float azb = t23 ? cr3.z : cr2.z, aub = t23 ? cr3.w : cr2.w;
      bool tf = kb < ka;
      unsigned lkey = tf ? kb : ka;
      float el = tf ? eb : ea; int pl = tf ? pb : pa; int nl = tf ? nb2 : na;
      float nx = tf ? axb : axa, ny = tf ? ayb : aya;
      float nz = tf ? azb : aza, nu = tf ? aub : aua;

      unsigned best = wave_min_u32(lkey);  // uniform after readlane(63)
      int jstar = (int)(best & 0xFFu);
      int w = jstar >> 2;  // winner lane; its local pick == jstar&3

      if (lane == w) {  // publish scanned-col state (off-chain stores)
        short_l[jstar] = el;
        path_l[jstar] = pl;
      }
      sc0 |= (cid0 == jstar); sc1 |= (cid1 == jstar);
      sc2 |= (cid2 == jstar); sc3 |= (cid3 == jstar);

      min_val = __int_as_float(__builtin_amdgcn_readlane(__float_as_int(el), w));
      int nr = __builtin_amdgcn_readlane(nl, w);
      if (nr < 0) { sink = jstar; break; }
      i = nr;
      xi = __int_as_float(__builtin_amdgcn_readlane(__float_as_int(nx), w));
      yi = __int_as_float(__builtin_amdgcn_readlane(__float_as_int(ny), w));
      zi = __int_as_float(__builtin_amdgcn_readlane(__float_as_int(nz), w));
      ui = __int_as_float(__builtin_amdgcn_readlane(__float_as_int(nu), w));
    }
    __syncthreads();  // publish short_l / path_l / sr_l

    // Dual update (rows via LDS flags, cols via register state).
#define DUALU(c) { int row = cid##c; \
      if (sr_l[row]) { \
        float du = (row == cur_row) ? min_val : (min_val - short_l[c4r_l[row]]); \
        rowd[row].w += du; } \
      if (sc##c) vv##c -= min_val - sh##c; }
    DUALU(0) DUALU(1) DUALU(2) DUALU(3)
#undef DUALU
    __syncthreads();

    if (lane == 0) {  // augment along the alternating path
      int jj = sink;
      while (true) {
        int ii = path_l[jj];
        r4c_l[jj] = ii;
        int tmp = c4r_l[ii];
        c4r_l[ii] = jj;
        jj = tmp;
        if (ii == cur_row) break;
      }
    }
    __syncthreads();
    rc0 = r4c_l[cid0]; rc1 = r4c_l[cid1]; rc2 = r4c_l[cid2]; rc3 = r4c_l[cid3];
    __syncthreads();
  }

  // ---- Final loss: exact fp64 matched distances. ----
  double s = 0.0;
#define FIN(c) { int row = cid##c; int j = c4r_l[row]; float4 rd = rowd[row]; \
    s += dist3d((double)rd.x, (double)rd.y, (double)rd.z, \
                (double)ys0[j], (double)ys1[j], (double)ys2[j]); }
  FIN(0) FIN(1) FIN(2) FIN(3)
#undef FIN
  for (int m = 1; m < 64; m <<= 1) s += __shfl_xor(s, m);
  if (lane == 0) partial[b] = s;
}

__global__ void emd_finalize_kernel(const double* __restrict__ partial,
                                    float* __restrict__ out) {
  if (threadIdx.x == 0 && blockIdx.x == 0) {
    double s = 0.0;
    for (int b = 0; b < NB; ++b) s += partial[b];
    out[0] = (float)(s / (double)(NB * NPTS));
  }
}

extern "C" void kernel_launch(void* const* d_in, const int* in_sizes, int n_in,
                              void* d_out, int out_size, void* d_ws, size_t ws_size,
                              hipStream_t stream) {
  const float* pred = (const float*)d_in[0];
  const float* label = (const float*)d_in[1];
  double* partial = (double*)d_ws;  // 8 doubles
  emd_lsa_kernel<<<NB, 64, 0, stream>>>(pred, label, partial);
  emd_finalize_kernel<<<1, 64, 0, stream>>>(partial, (float*)d_out);
}

// Round 8
// 1278.403 us; speedup vs baseline: 1.7491x; 1.0581x over previous
//
#include <hip/hip_runtime.h>
#include <math.h>

#define NPTS 256
#define NB 8

#if __has_builtin(__builtin_amdgcn_sqrtf)
#define FSQRT __builtin_amdgcn_sqrtf
#else
#define FSQRT sqrtf
#endif

// Exact fp64 distance (contract off) for the final loss value.
__device__ __forceinline__ double dist3d(double ax, double ay, double az,
                                         double bx, double by, double bz) {
#pragma clang fp contract(off)
  double d0 = ax - bx;
  double d1 = ay - by;
  double d2 = az - bz;
  double s = d0 * d0;
  s = s + d1 * d1;
  s = s + d2 * d2;
  return sqrt(s);
}

__device__ __forceinline__ float distf(float ax, float ay, float az,
                                       float bx, float by, float bz) {
  float d0 = ax - bx, d1 = ay - by, d2 = az - bz;
  return FSQRT(d0 * d0 + d1 * d1 + d2 * d2);
}

// Wave64 min-reduce of a u32 via DPP (row_shr 1/2/4/8 + row_bcast 15/31),
// broadcast via readlane(63). Pure VALU/SALU — no LDS traffic.
__device__ __forceinline__ unsigned wave_min_u32(unsigned x) {
  unsigned r = x;
  r = min(r, (unsigned)__builtin_amdgcn_update_dpp((int)r, (int)r, 0x111, 0xF, 0xF, false));
  r = min(r, (unsigned)__builtin_amdgcn_update_dpp((int)r, (int)r, 0x112, 0xF, 0xF, false));
  r = min(r, (unsigned)__builtin_amdgcn_update_dpp((int)r, (int)r, 0x114, 0xF, 0xF, false));
  r = min(r, (unsigned)__builtin_amdgcn_update_dpp((int)r, (int)r, 0x118, 0xF, 0xF, false));
  r = min(r, (unsigned)__builtin_amdgcn_update_dpp((int)r, (int)r, 0x142, 0xF, 0xF, false));
  r = min(r, (unsigned)__builtin_amdgcn_update_dpp((int)r, (int)r, 0x143, 0xF, 0xF, false));
  return (unsigned)__builtin_amdgcn_readlane((int)r, 63);
}

// One block = one 64-lane wave per batch sample.
// LAPJV-style init: column reduction + greedy + REDUCTION TRANSFER
// (v[phi(i)] -= mu_i, u_i = mu_i — parallel Jacobi form, keeps dual
// feasibility + CS => SAP phase still exactly optimal), then the
// round-7 zero-LDS-read shortest-augmenting-path loop.
__global__ __launch_bounds__(64) void emd_lsa_kernel(
    const float* __restrict__ pred, const float* __restrict__ label,
    double* __restrict__ partial) {
  __shared__ float4 rowd[NPTS];   // {x0,x1,x2,u}
  __shared__ float4 colj[NPTS];   // {y0,y1,y2,v}
  __shared__ float short_l[NPTS]; // shortest[] for scanned cols
  __shared__ int path_l[NPTS];    // path[] for scanned cols
  __shared__ int c4r_l[NPTS];     // col4row
  __shared__ int r4c_l[NPTS];     // row4col
  __shared__ int sr_l[NPTS];      // scanned-row flags
  __shared__ int bcfr[NPTS];      // greedy claims
  __shared__ int fq[NPTS];        // free-row queue

  const int lane = threadIdx.x;
  const int b = blockIdx.x;
  const float* xg = pred + (size_t)b * NPTS * 3;
  const float* yg = label + (size_t)b * NPTS * 3;

  const int cid0 = lane * 4, cid1 = cid0 + 1, cid2 = cid0 + 2, cid3 = cid0 + 3;

  float q0x, q0y, q0z, q1x, q1y, q1z, q2x, q2y, q2z, q3x, q3y, q3z;
  float vv0, vv1, vv2, vv3;
  int rc0, rc1, rc2, rc3;

#define INITC(c) { int j = cid##c; \
    rowd[j] = make_float4(xg[j*3+0], xg[j*3+1], xg[j*3+2], 0.0f); \
    float t0 = yg[j*3+0], t1 = yg[j*3+1], t2 = yg[j*3+2]; \
    colj[j] = make_float4(t0, t1, t2, 0.0f); \
    q##c##x = t0; q##c##y = t1; q##c##z = t2; \
    c4r_l[j] = -1; r4c_l[j] = -1; bcfr[j] = 0x7FFFFFFF; }
  INITC(0) INITC(1) INITC(2) INITC(3)
#undef INITC
  __syncthreads();

  // ---- Column reduction: v[j] = min_i cost[i][j], argmin row. ----
  float mm0 = 3.4e38f, mm1 = 3.4e38f, mm2 = 3.4e38f, mm3 = 3.4e38f;
  int im0 = -1, im1 = -1, im2 = -1, im3 = -1;
  for (int i = 0; i < NPTS; ++i) {
    float4 rd = rowd[i];  // broadcast read; independent iterations pipeline
#define CRED(c) { float d = distf(rd.x, rd.y, rd.z, q##c##x, q##c##y, q##c##z); \
    bool u_ = d < mm##c; mm##c = u_ ? d : mm##c; im##c = u_ ? i : im##c; }
    CRED(0) CRED(1) CRED(2) CRED(3)
#undef CRED
  }
  vv0 = mm0; vv1 = mm1; vv2 = mm2; vv3 = mm3;
  colj[cid0].w = vv0; colj[cid1].w = vv1;
  colj[cid2].w = vv2; colj[cid3].w = vv3;
  atomicMin(&bcfr[im0], cid0);
  atomicMin(&bcfr[im1], cid1);
  atomicMin(&bcfr[im2], cid2);
  atomicMin(&bcfr[im3], cid3);
  __syncthreads();
  if (bcfr[im0] == cid0) { r4c_l[cid0] = im0; c4r_l[im0] = cid0; }
  if (bcfr[im1] == cid1) { r4c_l[cid1] = im1; c4r_l[im1] = cid1; }
  if (bcfr[im2] == cid2) { r4c_l[cid2] = im2; c4r_l[im2] = cid2; }
  if (bcfr[im3] == cid3) { r4c_l[cid3] = im3; c4r_l[im3] = cid3; }
  __syncthreads();

  // ---- Reduction transfer (parallel Jacobi): for assigned rows i,
  // mu_i = min_{j != phi(i)} (c_ij - v_j); v[phi(i)] -= mu_i; u_i = mu_i.
  // v only decreases and assigned edges stay tight => feasibility + CS kept.
  {
    float4 rD0 = rowd[cid0], rD1 = rowd[cid1], rD2 = rowd[cid2], rD3 = rowd[cid3];
    int ja0 = c4r_l[cid0], ja1 = c4r_l[cid1], ja2 = c4r_l[cid2], ja3 = c4r_l[cid3];
    float mu0 = 3.4e38f, mu1 = 3.4e38f, mu2 = 3.4e38f, mu3 = 3.4e38f;
    for (int j = 0; j < NPTS; ++j) {
      float4 cj = colj[j];  // broadcast read
#define RT(c) { float d = distf(rD##c.x, rD##c.y, rD##c.z, cj.x, cj.y, cj.z) - cj.w; \
      d = (j == ja##c) ? 3.4e38f : d; \
      mu##c = fminf(mu##c, d); }
      RT(0) RT(1) RT(2) RT(3)
#undef RT
    }
    // Lockstep wave: all scans complete before any write below executes.
    if (ja0 >= 0) { colj[ja0].w -= mu0; rowd[cid0].w = mu0; }
    if (ja1 >= 0) { colj[ja1].w -= mu1; rowd[cid1].w = mu1; }
    if (ja2 >= 0) { colj[ja2].w -= mu2; rowd[cid2].w = mu2; }
    if (ja3 >= 0) { colj[ja3].w -= mu3; rowd[cid3].w = mu3; }
  }
  __syncthreads();
  vv0 = colj[cid0].w; vv1 = colj[cid1].w;
  vv2 = colj[cid2].w; vv3 = colj[cid3].w;
  rc0 = r4c_l[cid0]; rc1 = r4c_l[cid1]; rc2 = r4c_l[cid2]; rc3 = r4c_l[cid3];

  // ---- Build free-row queue via ballot compaction. ----
  int nf;
  {
    int4 cc = *(int4*)&c4r_l[cid0];
    bool f0 = cc.x < 0, f1 = cc.y < 0, f2 = cc.z < 0, f3 = cc.w < 0;
    unsigned long long b0 = __ballot(f0), b1 = __ballot(f1);
    unsigned long long b2 = __ballot(f2), b3 = __ballot(f3);
    unsigned long long lt = (1ull << lane) - 1ull;
    int off = __popcll(b0 & lt) + __popcll(b1 & lt) + __popcll(b2 & lt) + __popcll(b3 & lt);
    if (f0) fq[off++] = cid0;
    if (f1) fq[off++] = cid1;
    if (f2) fq[off++] = cid2;
    if (f3) fq[off++] = cid3;
    nf = __popcll(b0) + __popcll(b1) + __popcll(b2) + __popcll(b3);
  }
  __syncthreads();

  const float INF = 3.4e38f;

  // ---- Shortest augmenting path for each free row (round-7 loop). ----
  for (int t = 0; t < nf; ++t) {
    int cur_row = fq[t];  // uniform broadcast

    float sh0 = INF, sh1 = INF, sh2 = INF, sh3 = INF;
    int pp0 = -1, pp1 = -1, pp2 = -1, pp3 = -1;
    int sc0 = 0, sc1 = 0, sc2 = 0, sc3 = 0;
    *(int4*)&sr_l[cid0] = make_int4(0, 0, 0, 0);

    // Assigned-row records for owned columns: constant during the search.
    float4 cr0 = rowd[rc0 < 0 ? 0 : rc0];
    float4 cr1 = rowd[rc1 < 0 ? 0 : rc1];
    float4 cr2 = rowd[rc2 < 0 ? 0 : rc2];
    float4 cr3 = rowd[rc3 < 0 ? 0 : rc3];

    float xi, yi, zi, ui;
    { float4 r0 = rowd[cur_row]; xi = r0.x; yi = r0.y; zi = r0.z; ui = r0.w; }
    __syncthreads();

    float min_val = 0.0f;
    int i = cur_row;
    int sink = -1;

    while (true) {
      sr_l[i] = 1;  // same addr+value from all lanes (write-collapse)
      float base = min_val - ui;
      unsigned k0, k1, k2, k3;
#define SSTEP(c) { float d = distf(xi, yi, zi, q##c##x, q##c##y, q##c##z); \
      float r = (base + d) - vv##c; \
      bool u_ = (r < sh##c) && (sc##c == 0); \
      sh##c = u_ ? r : sh##c; \
      pp##c = u_ ? i : pp##c; \
      unsigned kk = (__float_as_uint(fmaxf(sh##c, 0.0f)) & 0xFFFFFF00u) | (unsigned)cid##c; \
      k##c = sc##c ? 0xFFFFFFFFu : kk; }
      SSTEP(0) SSTEP(1) SSTEP(2) SSTEP(3)
#undef SSTEP
      // Local 4-way tournament; payload selects run parallel to the key ops.
      bool t01 = k1 < k0;
      unsigned ka = t01 ? k1 : k0;
      float ea = t01 ? sh1 : sh0; int pa = t01 ? pp1 : pp0; int na = t01 ? rc1 : rc0;
      float axa = t01 ? cr1.x : cr0.x, aya = t01 ? cr1.y : cr0.y;
      float aza = t01 ? cr1.z : cr0.z, aua = t01 ? cr1.w : cr0.w;
      bool t23 = k3 < k2;
      unsigned kb = t23 ? k3 : k2;
      float eb = t23 ? sh3 : sh2; int pb = t23 ? pp3 : pp2; int nb2 = t23 ? rc3 : rc2;
      float axb = t23 ? cr3.x : cr2.x, ayb = t23 ? cr3.y : cr2.y;
      float azb = t23 ? cr3.z : cr2.z, aub = t23 ? cr3.w : cr2.w;
      bool tf = kb < ka;
      unsigned lkey = tf ? kb : ka;
      float el = tf ? eb : ea; int pl = tf ? pb : pa; int nl = tf ? nb2 : na;
      float nx = tf ? axb : axa, ny = tf ? ayb : aya;
      float nz = tf ? azb : aza, nu = tf ? aub : aua;

      unsigned best = wave_min_u32(lkey);  // uniform after readlane(63)
      int jstar = (int)(best & 0xFFu);
      int w = jstar >> 2;  // winner lane; its local pick == jstar&3

      if (lane == w) {  // publish scanned-col state (off-chain stores)
        short_l[jstar] = el;
        path_l[jstar] = pl;
      }
      sc0 |= (cid0 == jstar); sc1 |= (cid1 == jstar);
      sc2 |= (cid2 == jstar); sc3 |= (cid3 == jstar);

      min_val = __int_as_float(__builtin_amdgcn_readlane(__float_as_int(el), w));
      int nr = __builtin_amdgcn_readlane(nl, w);
      if (nr < 0) { sink = jstar; break; }
      i = nr;
      xi = __int_as_float(__builtin_amdgcn_readlane(__float_as_int(nx), w));
      yi = __int_as_float(__builtin_amdgcn_readlane(__float_as_int(ny), w));
      zi = __int_as_float(__builtin_amdgcn_readlane(__float_as_int(nz), w));
      ui = __int_as_float(__builtin_amdgcn_readlane(__float_as_int(nu), w));
    }
    __syncthreads();  // publish short_l / path_l / sr_l

    // Dual update (rows via LDS flags, cols via register state).
#define DUALU(c) { int row = cid##c; \
      if (sr_l[row]) { \
        float du = (row == cur_row) ? min_val : (min_val - short_l[c4r_l[row]]); \
        rowd[row].w += du; } \
      if (sc##c) vv##c -= min_val - sh##c; }
    DUALU(0) DUALU(1) DUALU(2) DUALU(3)
#undef DUALU
    __syncthreads();

    if (lane == 0) {  // augment along the alternating path
      int jj = sink;
      while (true) {
        int ii = path_l[jj];
        r4c_l[jj] = ii;
        int tmp = c4r_l[ii];
        c4r_l[ii] = jj;
        jj = tmp;
        if (ii == cur_row) break;
      }
    }
    __syncthreads();
    rc0 = r4c_l[cid0]; rc1 = r4c_l[cid1]; rc2 = r4c_l[cid2]; rc3 = r4c_l[cid3];
    __syncthreads();
  }

  // ---- Final loss: exact fp64 matched distances. ----
  double s = 0.0;
#define FIN(c) { int row = cid##c; int j = c4r_l[row]; float4 rd = rowd[row]; \
    float4 cj = colj[j]; \
    s += dist3d((double)rd.x, (double)rd.y, (double)rd.z, \
                (double)cj.x, (double)cj.y, (double)cj.z); }
  FIN(0) FIN(1) FIN(2) FIN(3)
#undef FIN
  for (int m = 1; m < 64; m <<= 1) s += __shfl_xor(s, m);
  if (lane == 0) partial[b] = s;
}

__global__ void emd_finalize_kernel(const double* __restrict__ partial,
                                    float* __restrict__ out) {
  if (threadIdx.x == 0 && blockIdx.x == 0) {
    double s = 0.0;
    for (int b = 0; b < NB; ++b) s += partial[b];
    out[0] = (float)(s / (double)(NB * NPTS));
  }
}

extern "C" void kernel_launch(void* const* d_in, const int* in_sizes, int n_in,
                              void* d_out, int out_size, void* d_ws, size_t ws_size,
                              hipStream_t stream) {
  const float* pred = (const float*)d_in[0];
  const float* label = (const float*)d_in[1];
  double* partial = (double*)d_ws;  // 8 doubles
  emd_lsa_kernel<<<NB, 64, 0, stream>>>(pred, label, partial);
  emd_finalize_kernel<<<1, 64, 0, stream>>>(partial, (float*)d_out);
}